// Round 3
// baseline (607.132 us; speedup 1.0000x reference)
//
#include <hip/hip_runtime.h>

#define M_DIM 65536
#define K_DIM 2048
#define N_DIM 1024
#define EPSV 1e-5f

typedef __bf16 bf16;
typedef bf16 bf16x8 __attribute__((ext_vector_type(8)));
typedef bf16 bf16x4 __attribute__((ext_vector_type(4)));
typedef float f32x16 __attribute__((ext_vector_type(16)));

// monotone float <-> uint encoding for atomicMin on float
__device__ inline unsigned fenc(float f) {
    unsigned u = __float_as_uint(f);
    return (u & 0x80000000u) ? ~u : (u | 0x80000000u);
}
__device__ inline float fdec(unsigned e) {
    unsigned u = (e & 0x80000000u) ? (e & 0x7fffffffu) : ~e;
    return __uint_as_float(u);
}

__device__ __forceinline__ void gload_lds16(const bf16* g, bf16* l) {
    __builtin_amdgcn_global_load_lds(
        (const __attribute__((address_space(1))) unsigned int*)g,
        (__attribute__((address_space(3))) unsigned int*)l, 16, 0, 0);
}

// fp32 -> bf16 conversion, vectorized
__global__ void cvt_kernel(const float* __restrict__ in, bf16* __restrict__ out, long n4) {
    long i = (long)blockIdx.x * blockDim.x + threadIdx.x;
    long stride = (long)gridDim.x * blockDim.x;
    for (; i < n4; i += stride) {
        float4 v = ((const float4*)in)[i];
        bf16x4 h;
        h[0] = (bf16)v.x; h[1] = (bf16)v.y; h[2] = (bf16)v.z; h[3] = (bf16)v.w;
        ((bf16x4*)out)[i] = h;
    }
}

// Stage one [256 rows][32 k] bf16 half-tile (16 KB): 512 threads x 2
// global_load_lds(16B). LDS dest LINEAR (wave-uniform base + lane*16);
// XOR swizzle (granule ^= (row>>1)&3) applied to the GLOBAL source
// address (both-sides involution, rule 21). Proven conflict-free (R2: 0).
__device__ __forceinline__ void stage_half(const bf16* __restrict__ g0, int kbase,
                                           bf16* slot, int tid) {
#pragma unroll
    for (int i = 0; i < 2; ++i) {
        int gidx = i * 512 + tid;           // 16B granule id, 1024 per half-tile
        int row = gidx >> 2;                // 4 granules (64B) per row
        int gsw = (gidx & 3) ^ ((row >> 1) & 3);
        gload_lds16(g0 + (size_t)row * K_DIM + kbase + gsw * 8,
                    slot + (size_t)(i * 512 + (tid & 448)) * 8);  // wave-uniform base
    }
}

// LDS slots: A[parity][khalf], B[parity][khalf], each [256][32] bf16 = 16KB.
#define ASL(P, H) (lds + ((P) * 2 + (H)) * 8192)
#define BSL(P, H) (lds + 32768 + ((P) * 2 + (H)) * 8192)

// 256x256 tile, BK=64 as two K-halves of 32; 8 waves (2Mx4N), per-wave
// 128x64 output via 4x2 frags of mfma_f32_32x32x16_bf16 (2495 TF pipe).
// 4 fat phases per iteration (2 K-tiles): each phase = 12 ds_read_b128 +
// one half-tile stage (4 loads) + 32-MFMA cluster between barrier pairs.
// Counted vmcnt(4) at Q0/Q2 only. Fused GroupNorm+rowmin epilogue
// (group == wave's 64-col span).
__global__ __launch_bounds__(512, 2)
void gemm_fused(const bf16* __restrict__ Xb, const bf16* __restrict__ Wb,
                const float* __restrict__ gnw, const float* __restrict__ gnb,
                unsigned* __restrict__ rowmin) {
    extern __shared__ __align__(16) bf16 lds[];  // 128 KiB dynamic

    const int tid = threadIdx.x;
    const int wave = tid >> 6, lane = tid & 63;
    const int wr = wave >> 2, wc = wave & 3;     // 2 x 4 wave grid
    const int c31 = lane & 31, hi = lane >> 5;

    // T1: bijective XCD-chunked block swizzle (1024 % 8 == 0)
    const int bid = blockIdx.x;
    const int swz = (bid & 7) * 128 + (bid >> 3);
    const int bx = swz & 3, by = swz >> 2;
    const int brow = by * 256, bcol = bx * 256;

    const bf16* Arow = Xb + (size_t)brow * K_DIM;
    const bf16* Brow = Wb + (size_t)bcol * K_DIM;

    // per-lane LDS read offsets (bf16 units) for 32x32x16 fragments:
    // A-frag (m,kk): row = wr*128 + m*32 + c31, col granule = (kk*2+hi)^aswz
    const int aswz = (c31 >> 1) & 3;
    const int ax0 = ((0 + hi) ^ aswz) * 8;   // kk=0
    const int ax1 = ((2 + hi) ^ aswz) * 8;   // kk=1
    const int abase = (wr * 128 + c31) * 32;
    const int bbase = (wc * 64 + c31) * 32;

    f32x16 acc[4][2];
#pragma unroll
    for (int m = 0; m < 4; ++m)
#pragma unroll
        for (int n = 0; n < 2; ++n) acc[m][n] = 0.0f;

    // ---- prologue: S00, S01, S10 = 12 loads/thread ----
    stage_half(Arow, 0,  ASL(0, 0), tid);
    stage_half(Brow, 0,  BSL(0, 0), tid);
    stage_half(Arow, 32, ASL(0, 1), tid);
    stage_half(Brow, 32, BSL(0, 1), tid);
    stage_half(Arow, 64, ASL(1, 0), tid);
    stage_half(Brow, 64, BSL(1, 0), tid);

    bf16x8 af[4][2], bfr[2][2];

#define VMSYNC do {                                              \
        asm volatile("s_waitcnt vmcnt(4)" ::: "memory");          \
        __builtin_amdgcn_s_barrier();                             \
        asm volatile("" ::: "memory");                            \
    } while (0)

#define READ(P, H) {                                                              \
        _Pragma("unroll") for (int m = 0; m < 4; ++m) {                           \
            af[m][0] = *(const bf16x8*)(ASL(P, H) + abase + m * 1024 + ax0);      \
            af[m][1] = *(const bf16x8*)(ASL(P, H) + abase + m * 1024 + ax1);      \
        }                                                                         \
        _Pragma("unroll") for (int n = 0; n < 2; ++n) {                           \
            bfr[n][0] = *(const bf16x8*)(BSL(P, H) + bbase + n * 1024 + ax0);     \
            bfr[n][1] = *(const bf16x8*)(BSL(P, H) + bbase + n * 1024 + ax1);     \
        }                                                                         \
    }

#define MFMA_PH() do {                                                            \
        __builtin_amdgcn_s_barrier();                                             \
        asm volatile("s_waitcnt lgkmcnt(0)" ::: "memory");                        \
        __builtin_amdgcn_sched_barrier(0);                                        \
        __builtin_amdgcn_s_setprio(1);                                            \
        _Pragma("unroll") for (int kk = 0; kk < 2; ++kk)                          \
            _Pragma("unroll") for (int m = 0; m < 4; ++m)                         \
                _Pragma("unroll") for (int n = 0; n < 2; ++n)                     \
                    acc[m][n] = __builtin_amdgcn_mfma_f32_32x32x16_bf16(          \
                        af[m][kk], bfr[n][kk], acc[m][n], 0, 0, 0);               \
        __builtin_amdgcn_s_setprio(0);                                            \
        __builtin_amdgcn_sched_barrier(0);                                        \
        __builtin_amdgcn_s_barrier();                                             \
    } while (0)

    // ---- main loop: 16 iterations x 2 K-tiles (K=2048, BK=64) ----
    for (int i = 0; i < 16; ++i) {
        const int tb = 2 * i + 1;
        const int t2 = (2 * i + 2) & 31, t3 = (2 * i + 3) & 31;  // wrap: staged, never read
        // Q0: consume tile 2i kh0; stage tile 2i+1 kh1
        VMSYNC;
        READ(0, 0);
        stage_half(Arow, tb * 64 + 32, ASL(1, 1), tid);
        stage_half(Brow, tb * 64 + 32, BSL(1, 1), tid);
        MFMA_PH();
        // Q1: consume tile 2i kh1; stage tile 2i+2 kh0
        READ(0, 1);
        stage_half(Arow, t2 * 64, ASL(0, 0), tid);
        stage_half(Brow, t2 * 64, BSL(0, 0), tid);
        MFMA_PH();
        // Q2: consume tile 2i+1 kh0; stage tile 2i+2 kh1
        VMSYNC;
        READ(1, 0);
        stage_half(Arow, t2 * 64 + 32, ASL(0, 1), tid);
        stage_half(Brow, t2 * 64 + 32, BSL(0, 1), tid);
        MFMA_PH();
        // Q3: consume tile 2i+1 kh1; stage tile 2i+3 kh0
        READ(1, 1);
        stage_half(Arow, t3 * 64, ASL(1, 0), tid);
        stage_half(Brow, t3 * 64, BSL(1, 0), tid);
        MFMA_PH();
    }

    // ---- fused epilogue: GroupNorm (group == wave's 64-col span) + row min ----
    // 32x32 C/D layout: col = c31 (+n*32), row = (j&3) + 8*(j>>2) + 4*hi (+m*32).
    // The two 32-lane halves reduce two different rows concurrently.
    float gwv[2], gbv[2];
#pragma unroll
    for (int n = 0; n < 2; ++n) {
        int col = bcol + wc * 64 + n * 32 + c31;
        gwv[n] = gnw[col];
        gbv[n] = gnb[col];
    }
#pragma unroll
    for (int m = 0; m < 4; ++m) {
#pragma unroll
        for (int j = 0; j < 16; ++j) {
            float v0 = acc[m][0][j], v1 = acc[m][1][j];
            float s = v0 + v1;
            float ss = v0 * v0 + v1 * v1;
#pragma unroll
            for (int d = 1; d < 32; d <<= 1) {
                s += __shfl_xor(s, d);
                ss += __shfl_xor(ss, d);
            }
            float mean = s * (1.f / 64.f);
            float var = ss * (1.f / 64.f) - mean * mean;
            float rstd = rsqrtf(var + EPSV);
            float y0 = (v0 - mean) * rstd * gwv[0] + gbv[0];
            float y1 = (v1 - mean) * rstd * gwv[1] + gbv[1];
            float mn = fminf(y0, y1);
#pragma unroll
            for (int d = 1; d < 32; d <<= 1) mn = fminf(mn, __shfl_xor(mn, d));
            if (c31 == 0) {
                int row = brow + wr * 128 + m * 32 + (j & 3) + 8 * (j >> 2) + 4 * hi;
                atomicMin(&rowmin[row], fenc(mn));
            }
        }
    }
}

// out[m][n] = dec(rowmin[m]) + bias[n]
__global__ void bcast_kernel(const unsigned* __restrict__ rowmin,
                             const float* __restrict__ bias,
                             float* __restrict__ out) {
    const long total4 = (long)M_DIM * N_DIM / 4;
    long i = (long)blockIdx.x * blockDim.x + threadIdx.x;
    long stride = (long)gridDim.x * blockDim.x;
    for (; i < total4; i += stride) {
        int mrow = (int)(i >> 8);  // N/4 = 256 float4 per row
        int n4 = (int)(i & 255);
        float rm = fdec(rowmin[mrow]);
        float4 b = ((const float4*)bias)[n4];
        float4 o;
        o.x = rm + b.x; o.y = rm + b.y; o.z = rm + b.z; o.w = rm + b.w;
        ((float4*)out)[i] = o;
    }
}

extern "C" void kernel_launch(void* const* d_in, const int* in_sizes, int n_in,
                              void* d_out, int out_size, void* d_ws, size_t ws_size,
                              hipStream_t stream) {
    const float* x = (const float*)d_in[0];
    const float* w = (const float*)d_in[1];
    const float* gnw = (const float*)d_in[2];
    const float* gnb = (const float*)d_in[3];
    const float* bias = (const float*)d_in[4];

    unsigned char* ws = (unsigned char*)d_ws;
    unsigned* rowmin = (unsigned*)ws;                          // 256 KB
    bf16* wb = (bf16*)(ws + (size_t)M_DIM * 4);                // 4 MB
    bf16* xb = (bf16*)(ws + (size_t)M_DIM * 4 + (size_t)N_DIM * K_DIM * 2);  // 256 MB

    hipFuncSetAttribute((const void*)gemm_fused,
                        hipFuncAttributeMaxDynamicSharedMemorySize, 131072);

    hipMemsetAsync(rowmin, 0xFF, (size_t)M_DIM * 4, stream);   // +inf in encoding
    cvt_kernel<<<512, 256, 0, stream>>>(w, wb, (long)N_DIM * K_DIM / 4);
    cvt_kernel<<<4096, 256, 0, stream>>>(x, xb, (long)M_DIM * K_DIM / 4);

    gemm_fused<<<dim3(1024), 512, 131072, stream>>>(xb, wb, gnw, gnb, rowmin);

    bcast_kernel<<<2048, 256, 0, stream>>>(rowmin, bias, (float*)d_out);
}

// Round 4
// 521.299 us; speedup vs baseline: 1.1647x; 1.1647x over previous
//
#include <hip/hip_runtime.h>

#define M_DIM 65536
#define K_DIM 2048
#define N_DIM 1024
#define EPSV 1e-5f

typedef __bf16 bf16;
typedef bf16 bf16x8 __attribute__((ext_vector_type(8)));
typedef bf16 bf16x4 __attribute__((ext_vector_type(4)));
typedef float f32x4 __attribute__((ext_vector_type(4)));

// monotone float <-> uint encoding for atomicMin on float
__device__ inline unsigned fenc(float f) {
    unsigned u = __float_as_uint(f);
    return (u & 0x80000000u) ? ~u : (u | 0x80000000u);
}
__device__ inline float fdec(unsigned e) {
    unsigned u = (e & 0x80000000u) ? (e & 0x7fffffffu) : ~e;
    return __uint_as_float(u);
}

__device__ __forceinline__ void gload_lds16(const bf16* g, bf16* l) {
    __builtin_amdgcn_global_load_lds(
        (const __attribute__((address_space(1))) unsigned int*)g,
        (__attribute__((address_space(3))) unsigned int*)l, 16, 0, 0);
}

// fp32 -> bf16 conversion, vectorized
__global__ void cvt_kernel(const float* __restrict__ in, bf16* __restrict__ out, long n4) {
    long i = (long)blockIdx.x * blockDim.x + threadIdx.x;
    long stride = (long)gridDim.x * blockDim.x;
    for (; i < n4; i += stride) {
        float4 v = ((const float4*)in)[i];
        bf16x4 h;
        h[0] = (bf16)v.x; h[1] = (bf16)v.y; h[2] = (bf16)v.z; h[3] = (bf16)v.w;
        ((bf16x4*)out)[i] = h;
    }
}

// Stage one [256 rows][32 k] bf16 half-tile (16 KB) with 512 threads, 2
// global_load_lds(16B) per thread. LDS dest is LINEAR (wave-uniform base +
// lane*16, HW requirement); the XOR swizzle (granule ^= (row>>1)&3) is
// applied to the GLOBAL source address (rule 21: pre-swizzled source +
// swizzled read = both-sides involution). Proven conflict-free (R2: 0).
__device__ __forceinline__ void stage_half(const bf16* __restrict__ g0, int kbase,
                                           bf16* slot, int tid) {
#pragma unroll
    for (int i = 0; i < 2; ++i) {
        int gidx = i * 512 + tid;           // 16B granule id, 1024 per half-tile
        int row = gidx >> 2;                // 4 granules (64B) per row
        int gsw = (gidx & 3) ^ ((row >> 1) & 3);
        gload_lds16(g0 + (size_t)row * K_DIM + kbase + gsw * 8,
                    slot + (size_t)(i * 512 + (tid & 448)) * 8);  // wave-uniform base
    }
}

// LDS slot layout: A[parity][khalf], B[parity][khalf], each [256][32] bf16 = 16KB.
#define ASL(P, H) (lds + ((P) * 2 + (H)) * 8192)
#define BSL(P, H) (lds + 32768 + ((P) * 2 + (H)) * 8192)

// 256x256 tile, BK=64 split in two K-halves of 32; 8 waves (2Mx4N), per-wave
// 128x64 output (8x4 frags of 16x16x32). 8 phases per iteration covering 2
// K-tiles; counted vmcnt(4) at P0/P4 only; raw s_barrier pairs per phase;
// setprio around the MFMA cluster; NO sched_barrier/lgkm pins (m141: pinning
// costs ~40% — let the compiler emit fine-grained lgkmcnt interleave).
// Fused GroupNorm+rowmin epilogue: each wave's 64-col span == one group.
__global__ __launch_bounds__(512, 2)
void gemm_fused(const bf16* __restrict__ Xb, const bf16* __restrict__ Wb,
                const float* __restrict__ gnw, const float* __restrict__ gnb,
                unsigned* __restrict__ rowmin) {
    extern __shared__ __align__(16) bf16 lds[];  // 128 KiB dynamic

    const int tid = threadIdx.x;
    const int wave = tid >> 6, lane = tid & 63;
    const int wr = wave >> 2, wc = wave & 3;     // 2 x 4 wave grid
    const int q = lane >> 4, r = lane & 15;

    // T1: bijective XCD-chunked block swizzle (1024 blocks % 8 == 0)
    const int bid = blockIdx.x;
    const int swz = (bid & 7) * 128 + (bid >> 3);
    const int bx = swz & 3, by = swz >> 2;
    const int brow = by * 256, bcol = bx * 256;

    const bf16* Arow = Xb + (size_t)brow * K_DIM;
    const bf16* Brow = Wb + (size_t)bcol * K_DIM;

    // per-lane LDS read offsets (bf16 units); swizzle term (row>>1)&3 == (r>>1)&3
    const int gswr = (r >> 1) & 3;
    const int aoff = (wr * 128 + r) * 32 + (q ^ gswr) * 8;
    const int boff = (wc * 64 + r) * 32 + (q ^ gswr) * 8;

    f32x4 acc[8][4];
#pragma unroll
    for (int m = 0; m < 8; ++m)
#pragma unroll
        for (int n = 0; n < 4; ++n) acc[m][n] = 0.0f;

    // ---- prologue: tile0 (both halves) + tile1 khalf0 = 12 loads/thread ----
    stage_half(Arow, 0,  ASL(0, 0), tid);
    stage_half(Brow, 0,  BSL(0, 0), tid);
    stage_half(Arow, 32, ASL(0, 1), tid);
    stage_half(Brow, 32, BSL(0, 1), tid);
    stage_half(Arow, 64, ASL(1, 0), tid);
    stage_half(Brow, 64, BSL(1, 0), tid);

    bf16x8 af[4], bfr[4];

#define VMSYNC do {                                              \
        asm volatile("s_waitcnt vmcnt(4)" ::: "memory");          \
        __builtin_amdgcn_s_barrier();                             \
        asm volatile("" ::: "memory");                            \
    } while (0)

#define READ_A(P, H, MH) {                                                        \
        _Pragma("unroll") for (int m = 0; m < 4; ++m)                             \
            af[m] = *(const bf16x8*)(ASL(P, H) + aoff + ((MH) * 4 + m) * 512);    \
    }
#define READ_B(P, H) {                                                            \
        _Pragma("unroll") for (int n = 0; n < 4; ++n)                             \
            bfr[n] = *(const bf16x8*)(BSL(P, H) + boff + n * 512);                \
    }

#define MFMA_PH(MH) do {                                                          \
        __builtin_amdgcn_s_barrier();                                             \
        __builtin_amdgcn_s_setprio(1);                                            \
        _Pragma("unroll") for (int m = 0; m < 4; ++m)                             \
            _Pragma("unroll") for (int n = 0; n < 4; ++n)                         \
                acc[(MH) * 4 + m][n] = __builtin_amdgcn_mfma_f32_16x16x32_bf16(   \
                    af[m], bfr[n], acc[(MH) * 4 + m][n], 0, 0, 0);                \
        __builtin_amdgcn_s_setprio(0);                                            \
        __builtin_amdgcn_s_barrier();                                             \
    } while (0)

    // ---- main loop: 16 iterations x 2 K-tiles (K=2048, BK=64) ----
    for (int i = 0; i < 16; ++i) {
        const int tb = 2 * i + 1;
        const int t2 = (2 * i + 2) & 31, t3 = (2 * i + 3) & 31;  // wrap: staged, never read
        // P0: consume tile 2i kh0 (mh0); stage tile 2i+1 kh1
        VMSYNC;
        READ_A(0, 0, 0); READ_B(0, 0);
        stage_half(Arow, tb * 64 + 32, ASL(1, 1), tid);
        stage_half(Brow, tb * 64 + 32, BSL(1, 1), tid);
        MFMA_PH(0);
        // P1
        READ_A(0, 0, 1);
        MFMA_PH(1);
        // P2: consume tile 2i kh1; stage tile 2i+2 kh0 (A)
        READ_A(0, 1, 0); READ_B(0, 1);
        stage_half(Arow, t2 * 64, ASL(0, 0), tid);
        MFMA_PH(0);
        // P3: stage tile 2i+2 kh0 (B)
        READ_A(0, 1, 1);
        stage_half(Brow, t2 * 64, BSL(0, 0), tid);
        MFMA_PH(1);
        // P4: consume tile 2i+1 kh0; stage tile 2i+2 kh1
        VMSYNC;
        READ_A(1, 0, 0); READ_B(1, 0);
        stage_half(Arow, t2 * 64 + 32, ASL(0, 1), tid);
        stage_half(Brow, t2 * 64 + 32, BSL(0, 1), tid);
        MFMA_PH(0);
        // P5
        READ_A(1, 0, 1);
        MFMA_PH(1);
        // P6: consume tile 2i+1 kh1; stage tile 2i+3 kh0 (A)
        READ_A(1, 1, 0); READ_B(1, 1);
        stage_half(Arow, t3 * 64, ASL(1, 0), tid);
        MFMA_PH(0);
        // P7: stage tile 2i+3 kh0 (B)
        READ_A(1, 1, 1);
        stage_half(Brow, t3 * 64, BSL(1, 0), tid);
        MFMA_PH(1);
    }

    // ---- fused epilogue: GroupNorm (group == wave's 64-col span) + row min ----
    float gw[4], gb[4];
#pragma unroll
    for (int n = 0; n < 4; ++n) {
        int col = bcol + wc * 64 + n * 16 + r;
        gw[n] = gnw[col];
        gb[n] = gnb[col];
    }
#pragma unroll
    for (int m = 0; m < 8; ++m) {
#pragma unroll
        for (int j = 0; j < 4; ++j) {
            float s = 0.f, ss = 0.f;
#pragma unroll
            for (int n = 0; n < 4; ++n) {
                float v = acc[m][n][j];
                s += v; ss += v * v;
            }
#pragma unroll
            for (int d = 1; d < 16; d <<= 1) {
                s += __shfl_xor(s, d);
                ss += __shfl_xor(ss, d);
            }
            float mean = s * (1.f / 64.f);
            float var = ss * (1.f / 64.f) - mean * mean;
            float rstd = rsqrtf(var + EPSV);
            float mn = 3.4e38f;
#pragma unroll
            for (int n = 0; n < 4; ++n) {
                float y = (acc[m][n][j] - mean) * rstd * gw[n] + gb[n];
                mn = fminf(mn, y);
            }
#pragma unroll
            for (int d = 1; d < 16; d <<= 1) mn = fminf(mn, __shfl_xor(mn, d));
            if (r == 0)
                atomicMin(&rowmin[brow + wr * 128 + m * 16 + q * 4 + j], fenc(mn));
        }
    }
}

// out[m][n] = dec(rowmin[m]) + bias[n]
__global__ void bcast_kernel(const unsigned* __restrict__ rowmin,
                             const float* __restrict__ bias,
                             float* __restrict__ out) {
    const long total4 = (long)M_DIM * N_DIM / 4;
    long i = (long)blockIdx.x * blockDim.x + threadIdx.x;
    long stride = (long)gridDim.x * blockDim.x;
    for (; i < total4; i += stride) {
        int mrow = (int)(i >> 8);  // N/4 = 256 float4 per row
        int n4 = (int)(i & 255);
        float rm = fdec(rowmin[mrow]);
        float4 b = ((const float4*)bias)[n4];
        float4 o;
        o.x = rm + b.x; o.y = rm + b.y; o.z = rm + b.z; o.w = rm + b.w;
        ((float4*)out)[i] = o;
    }
}

extern "C" void kernel_launch(void* const* d_in, const int* in_sizes, int n_in,
                              void* d_out, int out_size, void* d_ws, size_t ws_size,
                              hipStream_t stream) {
    const float* x = (const float*)d_in[0];
    const float* w = (const float*)d_in[1];
    const float* gnw = (const float*)d_in[2];
    const float* gnb = (const float*)d_in[3];
    const float* bias = (const float*)d_in[4];

    unsigned char* ws = (unsigned char*)d_ws;
    unsigned* rowmin = (unsigned*)ws;                          // 256 KB
    bf16* wb = (bf16*)(ws + (size_t)M_DIM * 4);                // 4 MB
    bf16* xb = (bf16*)(ws + (size_t)M_DIM * 4 + (size_t)N_DIM * K_DIM * 2);  // 256 MB

    hipFuncSetAttribute((const void*)gemm_fused,
                        hipFuncAttributeMaxDynamicSharedMemorySize, 131072);

    hipMemsetAsync(rowmin, 0xFF, (size_t)M_DIM * 4, stream);   // +inf in encoding
    cvt_kernel<<<512, 256, 0, stream>>>(w, wb, (long)N_DIM * K_DIM / 4);
    cvt_kernel<<<4096, 256, 0, stream>>>(x, xb, (long)M_DIM * K_DIM / 4);

    gemm_fused<<<dim3(1024), 512, 131072, stream>>>(xb, wb, gnw, gnb, rowmin);

    bcast_kernel<<<2048, 256, 0, stream>>>(rowmin, bias, (float*)d_out);
}